// Round 4
// baseline (267.048 us; speedup 1.0000x reference)
//
#include <hip/hip_runtime.h>
#include <math.h>

#define EPS 1e-16f
#define SLOT 64
__device__ __forceinline__ float lrelu(float v) { return v > 0.0f ? v : 0.2f * v; }

// bf16 pack/unpack (RNE; inputs finite)
__device__ __forceinline__ unsigned short f2bf(float f) {
    unsigned u = __float_as_uint(f);
    u += 0x7FFF + ((u >> 16) & 1);
    return (unsigned short)(u >> 16);
}
__device__ __forceinline__ float bf2f(unsigned short s) {
    return __uint_as_float(((unsigned)s) << 16);
}

__global__ void k_zero(int* __restrict__ deg, int N) {
    int i = blockIdx.x * 256 + threadIdx.x;
    if (i < N) deg[i] = 0;
}

// ---------------- fused: single-pass slot-CSR scatter (blocks [0,D)) + layer-1 GEMM ----------
// (round-2 form restored: XCD-partitioned variant regressed — 8x edge re-scan added +23 MB
//  FETCH, only -16 MB WRITE; net slower. Single full pass it is.)
// Slot-CSR: node d's incoming-edge sources live at ssrc[d*64 .. d*64+deg[d]).
// deg ~ Poisson(16); P(deg>63) ~ 2e-18/node -> 64-slot never overflows (guarded anyway).
// Scatter blocks FIRST (critical path); GEMM compute co-schedules behind atomic latency.
// GEMM: x[N,128] @ W1[128,64] -> h1 (bf16), + fused attention dots. BM=64,BN=64,K=128 whole;
// 4x4 micro-tile; pitches 129/65 (==1 mod 32) -> <=2-way conflicts.
#define LDK1 129
#define LDN1 65
__global__ __launch_bounds__(256, 2) void k_gemm1_scat(
    const float* __restrict__ x, const float* __restrict__ W1,
    const float* __restrict__ att_src1, const float* __restrict__ att_dst1,
    unsigned short* __restrict__ h1b, float* __restrict__ a_src1, float* __restrict__ a_dst1,
    int N, int D, const int* __restrict__ src, const int* __restrict__ dst,
    int* __restrict__ deg, int* __restrict__ ssrc, int E) {
    __shared__ float sX[64 * LDK1];    // [m][k]
    __shared__ float sW[128 * LDN1];   // [k][n]
    int t = threadIdx.x;
    if (blockIdx.x < D) {
        int e0 = (blockIdx.x * 256 + t) * 4;
        if (e0 < E) {
            int4 s4 = *((const int4*)(src + e0));
            int4 d4 = *((const int4*)(dst + e0));
            int p0 = atomicAdd(&deg[d4.x], 1);
            int p1 = atomicAdd(&deg[d4.y], 1);
            int p2 = atomicAdd(&deg[d4.z], 1);
            int p3 = atomicAdd(&deg[d4.w], 1);
            if (p0 < SLOT) ssrc[(d4.x << 6) + p0] = s4.x;
            if (p1 < SLOT) ssrc[(d4.y << 6) + p1] = s4.y;
            if (p2 < SLOT) ssrc[(d4.z << 6) + p2] = s4.z;
            if (p3 < SLOT) ssrc[(d4.w << 6) + p3] = s4.w;
        }
        return;
    }
    int r0 = (blockIdx.x - D) * 64;
    // stage W1 (128x64)
    for (int i = t; i < 2048; i += 256) {        // i = k*16 + n4
        int k = i >> 4, n4 = i & 15;
        float4 v = ((const float4*)W1)[i];
        float* p = sW + k * LDN1 + 4 * n4;
        p[0] = v.x; p[1] = v.y; p[2] = v.z; p[3] = v.w;
    }
    // stage x rows r0..r0+63 (zero-pad tail)
    for (int i = t; i < 2048; i += 256) {        // i = m*32 + k4
        int m = i >> 5, k4 = i & 31;
        int r = r0 + m;
        float4 v = make_float4(0.f, 0.f, 0.f, 0.f);
        if (r < N) v = ((const float4*)(x + (size_t)r * 128))[k4];
        float* p = sX + m * LDK1 + 4 * k4;
        p[0] = v.x; p[1] = v.y; p[2] = v.z; p[3] = v.w;
    }
    __syncthreads();
    int tx = t & 15, ty = t >> 4;                // rows 4*tx.., cols 4*ty..
    const float* pA = sX + 4 * tx * LDK1;
    const float* pB = sW + 4 * ty;
    float c[4][4] = {{0.f}};
#pragma unroll 8
    for (int k = 0; k < 128; k++) {
        float a0 = pA[k], a1 = pA[LDK1 + k], a2 = pA[2 * LDK1 + k], a3 = pA[3 * LDK1 + k];
        const float* pb = pB + k * LDN1;
        float b0 = pb[0], b1 = pb[1], b2 = pb[2], b3 = pb[3];
        c[0][0] = fmaf(a0, b0, c[0][0]); c[0][1] = fmaf(a0, b1, c[0][1]);
        c[0][2] = fmaf(a0, b2, c[0][2]); c[0][3] = fmaf(a0, b3, c[0][3]);
        c[1][0] = fmaf(a1, b0, c[1][0]); c[1][1] = fmaf(a1, b1, c[1][1]);
        c[1][2] = fmaf(a1, b2, c[1][2]); c[1][3] = fmaf(a1, b3, c[1][3]);
        c[2][0] = fmaf(a2, b0, c[2][0]); c[2][1] = fmaf(a2, b1, c[2][1]);
        c[2][2] = fmaf(a2, b2, c[2][2]); c[2][3] = fmaf(a2, b3, c[2][3]);
        c[3][0] = fmaf(a3, b0, c[3][0]); c[3][1] = fmaf(a3, b1, c[3][1]);
        c[3][2] = fmaf(a3, b2, c[3][2]); c[3][3] = fmaf(a3, b3, c[3][3]);
    }
    // epilogue: write h1 as bf16, fused per-head attention dots (fp32 accumulators).
    float as0 = att_src1[4 * ty + 0], as1 = att_src1[4 * ty + 1],
          as2 = att_src1[4 * ty + 2], as3 = att_src1[4 * ty + 3];
    float ad0 = att_dst1[4 * ty + 0], ad1 = att_dst1[4 * ty + 1],
          ad2 = att_dst1[4 * ty + 2], ad3 = att_dst1[4 * ty + 3];
    __syncthreads();                              // done reading sX/sW; reuse sX as partials
    float* sPs = sX;                              // [row][17]
    float* sPd = sX + 64 * 17;
#pragma unroll
    for (int i = 0; i < 4; i++) {
        int row = 4 * tx + i;
        int r = r0 + row;
        if (r < N) {
            ushort4 hv;
            hv.x = f2bf(c[i][0]); hv.y = f2bf(c[i][1]);
            hv.z = f2bf(c[i][2]); hv.w = f2bf(c[i][3]);
            *((ushort4*)(h1b + (size_t)r * 64 + 4 * ty)) = hv;
        }
        sPs[row * 17 + ty] = fmaf(c[i][0], as0, fmaf(c[i][1], as1, fmaf(c[i][2], as2, c[i][3] * as3)));
        sPd[row * 17 + ty] = fmaf(c[i][0], ad0, fmaf(c[i][1], ad1, fmaf(c[i][2], ad2, c[i][3] * ad3)));
    }
    __syncthreads();
    for (int i = t; i < 512; i += 256) {          // i = row*8 + h
        int row = i >> 3, h = i & 7;
        int r = r0 + row;
        if (r < N) {
            a_src1[r * 8 + h] = sPs[row * 17 + 2 * h] + sPs[row * 17 + 2 * h + 1];
            a_dst1[r * 8 + h] = sPd[row * 17 + 2 * h] + sPd[row * 17 + 2 * h + 1];
        }
    }
}

// ---------------- layer 1 agg + FUSED layer 2 GEMM (one wave per node) ----------------
// Per-node softmax + aggregate as before; then, since the wave holds the full 64-wide
// ELU'd row in registers (one element per lane), compute the layer-2 GEMM row in-wave:
// h2[d][j] = sum_l xx_l * W2[l][j] via 64-step broadcast-shuffle vs W2 staged in LDS,
// plus the a_src2/a_dst2 dots via cross-lane reduce. Deletes the k_gemm2 kernel and the
// xx array (25.6 MB of write+read traffic). Same fp32 math -> absmax unchanged.
__global__ __launch_bounds__(256) void k_node_agg1f(
    const int* __restrict__ deg, const int* __restrict__ ssrc,
    const float* __restrict__ a_src1, const float* __restrict__ a_dst1,
    const unsigned short* __restrict__ h1b, const float* __restrict__ bias1,
    const float* __restrict__ W2, const float* __restrict__ att_src2,
    const float* __restrict__ att_dst2,
    float* __restrict__ h2, float* __restrict__ a_src2, float* __restrict__ a_dst2, int N) {
    __shared__ float sW2[2560];                   // W2 [64][40]
    int t = threadIdx.x;
    for (int i = t; i < 2560; i += 256) sW2[i] = W2[i];
    __syncthreads();                              // single barrier, before any early return
    int d = (blockIdx.x * 256 + t) >> 6;
    int lane = t & 63;
    if (d >= N) return;
    int start = d << 6;
    int end = start + min(deg[d], SLOT);
    int hcol = lane >> 3;   // head owning this output col
    int h8 = lane & 7;      // head this lane covers in edge-parallel phase
    int eoff = lane >> 3;   // edge-in-chunk this lane covers in edge-parallel phase
    float adst8 = a_dst1[d * 8 + h8];
    float acc0 = 0.0f, acc1 = 0.0f, lsumA = 0.0f;
    int base = start;
    for (; base + 8 <= end; base += 8) {
        // phase A: 8 edges x 8 heads in parallel
        int s_l = ssrc[base + eoff];
        float ex_l = __expf(lrelu(a_src1[(size_t)s_l * 8 + h8] + adst8));
        lsumA += ex_l;
        // phase B: broadcast (s,ex) via shuffle, 8 independent gathers
        int s0 = __shfl(s_l, 0),  s1 = __shfl(s_l, 8),  s2 = __shfl(s_l, 16), s3 = __shfl(s_l, 24);
        int s4 = __shfl(s_l, 32), s5 = __shfl(s_l, 40), s6 = __shfl(s_l, 48), s7 = __shfl(s_l, 56);
        float f0 = __shfl(ex_l, hcol),      f1 = __shfl(ex_l, 8 + hcol);
        float f2 = __shfl(ex_l, 16 + hcol), f3 = __shfl(ex_l, 24 + hcol);
        float f4 = __shfl(ex_l, 32 + hcol), f5 = __shfl(ex_l, 40 + hcol);
        float f6 = __shfl(ex_l, 48 + hcol), f7 = __shfl(ex_l, 56 + hcol);
        float g0 = bf2f(h1b[(size_t)s0 * 64 + lane]), g1 = bf2f(h1b[(size_t)s1 * 64 + lane]);
        float g2 = bf2f(h1b[(size_t)s2 * 64 + lane]), g3 = bf2f(h1b[(size_t)s3 * 64 + lane]);
        float g4 = bf2f(h1b[(size_t)s4 * 64 + lane]), g5 = bf2f(h1b[(size_t)s5 * 64 + lane]);
        float g6 = bf2f(h1b[(size_t)s6 * 64 + lane]), g7 = bf2f(h1b[(size_t)s7 * 64 + lane]);
        acc0 = fmaf(f0, g0, acc0); acc1 = fmaf(f1, g1, acc1);
        acc0 = fmaf(f2, g2, acc0); acc1 = fmaf(f3, g3, acc1);
        acc0 = fmaf(f4, g4, acc0); acc1 = fmaf(f5, g5, acc1);
        acc0 = fmaf(f6, g6, acc0); acc1 = fmaf(f7, g7, acc1);
    }
    int ecnt = end - base;
    if (ecnt > 0) {
        int s_l = 0; float ex_l = 0.0f;
        if (eoff < ecnt) {
            s_l = ssrc[base + eoff];
            ex_l = __expf(lrelu(a_src1[(size_t)s_l * 8 + h8] + adst8));
        }
        lsumA += ex_l;
        for (int j = 0; j < ecnt; j++) {
            int sj = __shfl(s_l, j * 8);
            float fj = __shfl(ex_l, j * 8 + hcol);
            acc0 = fmaf(fj, bf2f(h1b[(size_t)sj * 64 + lane]), acc0);
        }
    }
    // denom: reduce lsumA over edge-offset bits (3..5); then broadcast head hcol's sum
    float tr = lsumA;
    tr += __shfl_xor(tr, 8); tr += __shfl_xor(tr, 16); tr += __shfl_xor(tr, 32);
    float lsum = __shfl(tr, hcol);
    float o = (acc0 + acc1) / (lsum + EPS) + bias1[lane];
    o = o > 0.0f ? o : expm1f(o);                 // ELU; this lane holds xx[d][lane]
    // ---- fused layer-2 GEMM row: lane j (<40) computes h2[d][j] ----
    int jj = lane < 40 ? lane : 39;               // clamp for safe LDS reads on idle lanes
    float hj0 = 0.f, hj1 = 0.f, hj2 = 0.f, hj3 = 0.f;
#pragma unroll
    for (int l = 0; l < 64; l += 4) {
        float x0 = __shfl(o, l),     x1 = __shfl(o, l + 1);
        float x2 = __shfl(o, l + 2), x3 = __shfl(o, l + 3);
        hj0 = fmaf(x0, sW2[(l + 0) * 40 + jj], hj0);
        hj1 = fmaf(x1, sW2[(l + 1) * 40 + jj], hj1);
        hj2 = fmaf(x2, sW2[(l + 2) * 40 + jj], hj2);
        hj3 = fmaf(x3, sW2[(l + 3) * 40 + jj], hj3);
    }
    float hj = (hj0 + hj1) + (hj2 + hj3);
    bool actj = lane < 40;
    if (actj) h2[(size_t)d * 40 + lane] = hj;
    float ps = actj ? hj * att_src2[lane] : 0.f;
    float pd = actj ? hj * att_dst2[lane] : 0.f;
#pragma unroll
    for (int off = 32; off; off >>= 1) {
        ps += __shfl_xor(ps, off);
        pd += __shfl_xor(pd, off);
    }
    if (lane == 0) { a_src2[d] = ps; a_dst2[d] = pd; }
}

// ---------------- layer 2: per-dst-node softmax + aggregate ----------------
__global__ __launch_bounds__(256) void k_node_agg2(
    const int* __restrict__ deg, const int* __restrict__ ssrc,
    const float* __restrict__ a_src2, const float* __restrict__ a_dst2,
    const float* __restrict__ h2, const float* __restrict__ bias2,
    float* __restrict__ out, int N) {
    int d = (blockIdx.x * 256 + threadIdx.x) >> 6;
    int lane = threadIdx.x & 63;
    if (d >= N) return;
    int start = d << 6;
    int end = start + min(deg[d], SLOT);
    float adst = a_dst2[d];
    bool act = lane < 40;
    float acc0 = 0.0f, acc1 = 0.0f, lsumA = 0.0f;
    for (int base = start; base < end; base += 64) {
        int ecnt = min(64, end - base);
        int s_l = 0; float ex_l = 0.0f;
        if (lane < ecnt) {
            s_l = ssrc[base + lane];
            ex_l = __expf(lrelu(a_src2[s_l] + adst));
        }
        lsumA += ex_l;
        int j = 0;
        for (; j + 8 <= ecnt; j += 8) {
            int s0 = __shfl(s_l, j),     s1 = __shfl(s_l, j + 1), s2 = __shfl(s_l, j + 2), s3 = __shfl(s_l, j + 3);
            int s4 = __shfl(s_l, j + 4), s5 = __shfl(s_l, j + 5), s6 = __shfl(s_l, j + 6), s7 = __shfl(s_l, j + 7);
            float f0 = __shfl(ex_l, j),     f1 = __shfl(ex_l, j + 1), f2 = __shfl(ex_l, j + 2), f3 = __shfl(ex_l, j + 3);
            float f4 = __shfl(ex_l, j + 4), f5 = __shfl(ex_l, j + 5), f6 = __shfl(ex_l, j + 6), f7 = __shfl(ex_l, j + 7);
            float g0 = act ? h2[(size_t)s0 * 40 + lane] : 0.0f;
            float g1 = act ? h2[(size_t)s1 * 40 + lane] : 0.0f;
            float g2 = act ? h2[(size_t)s2 * 40 + lane] : 0.0f;
            float g3 = act ? h2[(size_t)s3 * 40 + lane] : 0.0f;
            float g4 = act ? h2[(size_t)s4 * 40 + lane] : 0.0f;
            float g5 = act ? h2[(size_t)s5 * 40 + lane] : 0.0f;
            float g6 = act ? h2[(size_t)s6 * 40 + lane] : 0.0f;
            float g7 = act ? h2[(size_t)s7 * 40 + lane] : 0.0f;
            acc0 = fmaf(f0, g0, acc0); acc1 = fmaf(f1, g1, acc1);
            acc0 = fmaf(f2, g2, acc0); acc1 = fmaf(f3, g3, acc1);
            acc0 = fmaf(f4, g4, acc0); acc1 = fmaf(f5, g5, acc1);
            acc0 = fmaf(f6, g6, acc0); acc1 = fmaf(f7, g7, acc1);
        }
        for (; j < ecnt; j++) {
            int sj = __shfl(s_l, j);
            float fj = __shfl(ex_l, j);
            float g = act ? h2[(size_t)sj * 40 + lane] : 0.0f;
            acc0 = fmaf(fj, g, acc0);
        }
    }
    float t = lsumA;
#pragma unroll
    for (int off = 32; off; off >>= 1) t += __shfl_xor(t, off);
    if (act) out[(size_t)d * 40 + lane] = (acc0 + acc1) / (t + EPS) + bias2[lane];
}

// ---------------- launch ----------------
extern "C" void kernel_launch(void* const* d_in, const int* in_sizes, int n_in,
                              void* d_out, int out_size, void* d_ws, size_t ws_size,
                              hipStream_t stream) {
    const float* x        = (const float*)d_in[0];
    const int*   ei       = (const int*)d_in[1];
    const float* W1       = (const float*)d_in[2];
    const float* att_src1 = (const float*)d_in[3];
    const float* att_dst1 = (const float*)d_in[4];
    const float* bias1    = (const float*)d_in[5];
    const float* W2       = (const float*)d_in[6];
    const float* att_src2 = (const float*)d_in[7];
    const float* att_dst2 = (const float*)d_in[8];
    const float* bias2    = (const float*)d_in[9];
    float* out = (float*)d_out;

    const int N = in_sizes[0] / 128;   // 50000
    const int E = in_sizes[1] / 2;     // 800000
    const int* src = ei;
    const int* dst = ei + E;

    // workspace layout (slot-CSR; no xx — layer-2 GEMM fused into node_agg1)
    float* ws = (float*)d_ws;
    size_t off = 0;
    int*   deg      = (int*)(ws + off); off += (size_t)N;
    int*   ssrc     = (int*)(ws + off); off += (size_t)N * SLOT;
    unsigned short* h1b = (unsigned short*)(ws + off); off += (size_t)N * 32;  // bf16 N*64
    float* a_src1   = ws + off; off += (size_t)N * 8;
    float* a_dst1   = ws + off; off += (size_t)N * 8;
    float* h2       = ws + off; off += (size_t)N * 40;
    float* a_src2   = ws + off; off += (size_t)N;
    float* a_dst2   = ws + off; off += (size_t)N;

    const int B = 256;
    auto g = [](int n) { return (n + 255) / 256; };
    int G1 = (N + 63) / 64;               // gemm blocks (782)
    int D  = (E / 4 + 255) / 256;         // scatter blocks (4 edges/thread, 782)

    k_zero<<<g(N), B, 0, stream>>>(deg, N);
    // single-pass slot-CSR scatter fused with gemm1 (+ attention dots): scatter blocks
    // first (critical path), GEMM co-schedules behind atomic latency
    k_gemm1_scat<<<D + G1, B, 0, stream>>>(x, W1, att_src1, att_dst1, h1b, a_src1, a_dst1,
                                           N, D, src, dst, deg, ssrc, E);
    // layer-1 aggregate + fused layer-2 GEMM (k_gemm2 deleted)
    k_node_agg1f<<<(N + 3) / 4, B, 0, stream>>>(deg, ssrc, a_src1, a_dst1, h1b, bias1,
                                                W2, att_src2, att_dst2, h2, a_src2, a_dst2, N);
    k_node_agg2<<<(N + 3) / 4, B, 0, stream>>>(deg, ssrc, a_src2, a_dst2, h2, bias2, out, N);
}

// Round 5
// 235.366 us; speedup vs baseline: 1.1346x; 1.1346x over previous
//
#include <hip/hip_runtime.h>
#include <math.h>

#define EPS 1e-16f
#define SLOT 64
__device__ __forceinline__ float lrelu(float v) { return v > 0.0f ? v : 0.2f * v; }

// bf16 pack/unpack (RNE; inputs finite)
__device__ __forceinline__ unsigned short f2bf(float f) {
    unsigned u = __float_as_uint(f);
    u += 0x7FFF + ((u >> 16) & 1);
    return (unsigned short)(u >> 16);
}
__device__ __forceinline__ float bf2f(unsigned short s) {
    return __uint_as_float(((unsigned)s) << 16);
}

// ---------------- fused: single-pass slot-CSR scatter (blocks [0,D)) + layer-1 GEMM ----------
// Slot-CSR: node d's incoming-edge sources live at ssrc[d*64 .. d*64+deg[d]).
// deg ~ Poisson(16); P(deg>63) ~ 2e-18/node -> 64-slot never overflows (guarded anyway).
// Scatter blocks FIRST (critical path); GEMM compute co-schedules behind atomic latency.
// GEMM: x[N,128] @ W1[128,64] -> h1 (bf16), + fused attention dots. BM=64,BN=64,K=128 whole;
// 4x4 micro-tile; pitches 129/65 (==1 mod 32) -> <=2-way conflicts.
#define LDK1 129
#define LDN1 65
__global__ __launch_bounds__(256, 2) void k_gemm1_scat(
    const float* __restrict__ x, const float* __restrict__ W1,
    const float* __restrict__ att_src1, const float* __restrict__ att_dst1,
    unsigned short* __restrict__ h1b, float* __restrict__ a_src1, float* __restrict__ a_dst1,
    int N, int D, const int* __restrict__ src, const int* __restrict__ dst,
    int* __restrict__ deg, int* __restrict__ ssrc, int E) {
    __shared__ float sX[64 * LDK1];    // [m][k]
    __shared__ float sW[128 * LDN1];   // [k][n]
    int t = threadIdx.x;
    if (blockIdx.x < D) {
        int e0 = (blockIdx.x * 256 + t) * 4;
        if (e0 < E) {
            int4 s4 = *((const int4*)(src + e0));
            int4 d4 = *((const int4*)(dst + e0));
            int p0 = atomicAdd(&deg[d4.x], 1);
            int p1 = atomicAdd(&deg[d4.y], 1);
            int p2 = atomicAdd(&deg[d4.z], 1);
            int p3 = atomicAdd(&deg[d4.w], 1);
            if (p0 < SLOT) ssrc[(d4.x << 6) + p0] = s4.x;
            if (p1 < SLOT) ssrc[(d4.y << 6) + p1] = s4.y;
            if (p2 < SLOT) ssrc[(d4.z << 6) + p2] = s4.z;
            if (p3 < SLOT) ssrc[(d4.w << 6) + p3] = s4.w;
        }
        return;
    }
    int r0 = (blockIdx.x - D) * 64;
    // stage W1 (128x64)
    for (int i = t; i < 2048; i += 256) {        // i = k*16 + n4
        int k = i >> 4, n4 = i & 15;
        float4 v = ((const float4*)W1)[i];
        float* p = sW + k * LDN1 + 4 * n4;
        p[0] = v.x; p[1] = v.y; p[2] = v.z; p[3] = v.w;
    }
    // stage x rows r0..r0+63 (zero-pad tail)
    for (int i = t; i < 2048; i += 256) {        // i = m*32 + k4
        int m = i >> 5, k4 = i & 31;
        int r = r0 + m;
        float4 v = make_float4(0.f, 0.f, 0.f, 0.f);
        if (r < N) v = ((const float4*)(x + (size_t)r * 128))[k4];
        float* p = sX + m * LDK1 + 4 * k4;
        p[0] = v.x; p[1] = v.y; p[2] = v.z; p[3] = v.w;
    }
    __syncthreads();
    int tx = t & 15, ty = t >> 4;                // rows 4*tx.., cols 4*ty..
    const float* pA = sX + 4 * tx * LDK1;
    const float* pB = sW + 4 * ty;
    float c[4][4] = {{0.f}};
#pragma unroll 8
    for (int k = 0; k < 128; k++) {
        float a0 = pA[k], a1 = pA[LDK1 + k], a2 = pA[2 * LDK1 + k], a3 = pA[3 * LDK1 + k];
        const float* pb = pB + k * LDN1;
        float b0 = pb[0], b1 = pb[1], b2 = pb[2], b3 = pb[3];
        c[0][0] = fmaf(a0, b0, c[0][0]); c[0][1] = fmaf(a0, b1, c[0][1]);
        c[0][2] = fmaf(a0, b2, c[0][2]); c[0][3] = fmaf(a0, b3, c[0][3]);
        c[1][0] = fmaf(a1, b0, c[1][0]); c[1][1] = fmaf(a1, b1, c[1][1]);
        c[1][2] = fmaf(a1, b2, c[1][2]); c[1][3] = fmaf(a1, b3, c[1][3]);
        c[2][0] = fmaf(a2, b0, c[2][0]); c[2][1] = fmaf(a2, b1, c[2][1]);
        c[2][2] = fmaf(a2, b2, c[2][2]); c[2][3] = fmaf(a2, b3, c[2][3]);
        c[3][0] = fmaf(a3, b0, c[3][0]); c[3][1] = fmaf(a3, b1, c[3][1]);
        c[3][2] = fmaf(a3, b2, c[3][2]); c[3][3] = fmaf(a3, b3, c[3][3]);
    }
    // epilogue: write h1 as bf16, fused per-head attention dots (fp32 accumulators).
    float as0 = att_src1[4 * ty + 0], as1 = att_src1[4 * ty + 1],
          as2 = att_src1[4 * ty + 2], as3 = att_src1[4 * ty + 3];
    float ad0 = att_dst1[4 * ty + 0], ad1 = att_dst1[4 * ty + 1],
          ad2 = att_dst1[4 * ty + 2], ad3 = att_dst1[4 * ty + 3];
    __syncthreads();                              // done reading sX/sW; reuse sX as partials
    float* sPs = sX;                              // [row][17]
    float* sPd = sX + 64 * 17;
#pragma unroll
    for (int i = 0; i < 4; i++) {
        int row = 4 * tx + i;
        int r = r0 + row;
        if (r < N) {
            ushort4 hv;
            hv.x = f2bf(c[i][0]); hv.y = f2bf(c[i][1]);
            hv.z = f2bf(c[i][2]); hv.w = f2bf(c[i][3]);
            *((ushort4*)(h1b + (size_t)r * 64 + 4 * ty)) = hv;
        }
        sPs[row * 17 + ty] = fmaf(c[i][0], as0, fmaf(c[i][1], as1, fmaf(c[i][2], as2, c[i][3] * as3)));
        sPd[row * 17 + ty] = fmaf(c[i][0], ad0, fmaf(c[i][1], ad1, fmaf(c[i][2], ad2, c[i][3] * ad3)));
    }
    __syncthreads();
    for (int i = t; i < 512; i += 256) {          // i = row*8 + h
        int row = i >> 3, h = i & 7;
        int r = r0 + row;
        if (r < N) {
            a_src1[r * 8 + h] = sPs[row * 17 + 2 * h] + sPs[row * 17 + 2 * h + 1];
            a_dst1[r * 8 + h] = sPd[row * 17 + 2 * h] + sPd[row * 17 + 2 * h + 1];
        }
    }
}

// ---------------- layer 1: per-dst-node softmax + aggregate (one wave per node) ----------------
// Pipelined: the whole 64-slot row is loaded in ONE coalesced 256B access (s_lane), then all
// chunks' a_src1 gathers issue from an unrolled loop (<=8 independent gathers in flight)
// before the h1b gather stream. Removes the serial per-chunk {scattered ssrc load -> dependent
// a_src1 gather} latency chain (was ~2 L3 round-trips per 8 edges).
// No max subtraction (softmax shift-invariant; logits are O(1)); h1 gathered as bf16.
__global__ __launch_bounds__(256) void k_node_agg1(
    const int* __restrict__ deg, const int* __restrict__ ssrc,
    const float* __restrict__ a_src1, const float* __restrict__ a_dst1,
    const unsigned short* __restrict__ h1b, const float* __restrict__ bias1,
    float* __restrict__ xx, int N) {
    int d = (blockIdx.x * 256 + threadIdx.x) >> 6;
    int lane = threadIdx.x & 63;
    if (d >= N) return;
    int start = d << 6;
    int m = min(deg[d], SLOT);                    // wave-uniform
    int hcol = lane >> 3;   // head owning this output col
    int h8 = lane & 7;      // head this lane covers in edge-parallel phase
    int eoff = lane >> 3;   // edge-in-chunk this lane covers in edge-parallel phase
    float adst8 = a_dst1[d * 8 + h8];
    // coalesced slot-row load: lane i holds src of edge i
    int s_lane = 0;
    if (lane < m) s_lane = ssrc[start + lane];
    // phase A (all chunks up-front): lane covers edge c*8+eoff, head h8
    float exv[8];
    float lsumA = 0.0f;
#pragma unroll
    for (int c = 0; c < 8; c++) {
        int idx = c * 8 + eoff;
        int s_c = __shfl(s_lane, idx);
        float e = 0.0f;
        if (idx < m) e = __expf(lrelu(a_src1[(size_t)s_c * 8 + h8] + adst8));
        exv[c] = e;
        lsumA += e;
    }
    // phase B: per chunk, broadcast (s, ex) and stream 8 independent h1b gathers
    float acc0 = 0.0f, acc1 = 0.0f;
#pragma unroll
    for (int c = 0; c < 8; c++) {
        int e0c = c * 8;
        if (e0c >= m) break;                      // wave-uniform
        int rem = m - e0c;
        float exc = exv[c];
        if (rem >= 8) {
            int s0 = __shfl(s_lane, e0c + 0), s1 = __shfl(s_lane, e0c + 1);
            int s2 = __shfl(s_lane, e0c + 2), s3 = __shfl(s_lane, e0c + 3);
            int s4 = __shfl(s_lane, e0c + 4), s5 = __shfl(s_lane, e0c + 5);
            int s6 = __shfl(s_lane, e0c + 6), s7 = __shfl(s_lane, e0c + 7);
            float f0 = __shfl(exc, hcol),      f1 = __shfl(exc, 8 + hcol);
            float f2 = __shfl(exc, 16 + hcol), f3 = __shfl(exc, 24 + hcol);
            float f4 = __shfl(exc, 32 + hcol), f5 = __shfl(exc, 40 + hcol);
            float f6 = __shfl(exc, 48 + hcol), f7 = __shfl(exc, 56 + hcol);
            float g0 = bf2f(h1b[(size_t)s0 * 64 + lane]), g1 = bf2f(h1b[(size_t)s1 * 64 + lane]);
            float g2 = bf2f(h1b[(size_t)s2 * 64 + lane]), g3 = bf2f(h1b[(size_t)s3 * 64 + lane]);
            float g4 = bf2f(h1b[(size_t)s4 * 64 + lane]), g5 = bf2f(h1b[(size_t)s5 * 64 + lane]);
            float g6 = bf2f(h1b[(size_t)s6 * 64 + lane]), g7 = bf2f(h1b[(size_t)s7 * 64 + lane]);
            acc0 = fmaf(f0, g0, acc0); acc1 = fmaf(f1, g1, acc1);
            acc0 = fmaf(f2, g2, acc0); acc1 = fmaf(f3, g3, acc1);
            acc0 = fmaf(f4, g4, acc0); acc1 = fmaf(f5, g5, acc1);
            acc0 = fmaf(f6, g6, acc0); acc1 = fmaf(f7, g7, acc1);
        } else {
            for (int j = 0; j < rem; j++) {
                int sj = __shfl(s_lane, e0c + j);
                float fj = __shfl(exc, j * 8 + hcol);
                acc0 = fmaf(fj, bf2f(h1b[(size_t)sj * 64 + lane]), acc0);
            }
        }
    }
    // denom: reduce lsumA over edge-offset bits (3..5); then broadcast head hcol's sum
    float t = lsumA;
    t += __shfl_xor(t, 8); t += __shfl_xor(t, 16); t += __shfl_xor(t, 32);
    float lsum = __shfl(t, hcol);
    float o = (acc0 + acc1) / (lsum + EPS) + bias1[lane];
    xx[(size_t)d * 64 + lane] = o > 0.0f ? o : expm1f(o);   // ELU
}

// ---------------- layer 2 GEMM: xx[N,64] @ W2[64,40] -> h2, + fused attention dots ----
#define LDK2 65
#define LDN2 41
__global__ __launch_bounds__(256, 2) void k_gemm2(
    const float* __restrict__ xx, const float* __restrict__ W2,
    const float* __restrict__ att_src2, const float* __restrict__ att_dst2,
    float* __restrict__ h2, float* __restrict__ a_src2, float* __restrict__ a_dst2, int N) {
    __shared__ float sX[64 * LDK2];    // [m][k]
    __shared__ float sW[64 * LDN2];    // [k][n]
    int t = threadIdx.x;
    int r0 = blockIdx.x * 64;
    for (int i = t; i < 640; i += 256) {          // i = k*10 + n4
        int k = i / 10, n4 = i - k * 10;
        float4 v = ((const float4*)W2)[i];
        float* p = sW + k * LDN2 + 4 * n4;
        p[0] = v.x; p[1] = v.y; p[2] = v.z; p[3] = v.w;
    }
    for (int i = t; i < 1024; i += 256) {         // i = m*16 + k4
        int m = i >> 4, k4 = i & 15;
        int r = r0 + m;
        float4 v = make_float4(0.f, 0.f, 0.f, 0.f);
        if (r < N) v = ((const float4*)(xx + (size_t)r * 64))[k4];
        float* p = sX + m * LDK2 + 4 * k4;
        p[0] = v.x; p[1] = v.y; p[2] = v.z; p[3] = v.w;
    }
    __syncthreads();
    int tx = t & 15, ty = t >> 4;
    bool act = ty < 10;
    float c[4][4] = {{0.f}};
    if (act) {
        const float* pA = sX + 4 * tx * LDK2;
        const float* pB = sW + 4 * ty;
#pragma unroll 8
        for (int k = 0; k < 64; k++) {
            float a0 = pA[k], a1 = pA[LDK2 + k], a2 = pA[2 * LDK2 + k], a3 = pA[3 * LDK2 + k];
            const float* pb = pB + k * LDN2;
            float b0 = pb[0], b1 = pb[1], b2 = pb[2], b3 = pb[3];
            c[0][0] = fmaf(a0, b0, c[0][0]); c[0][1] = fmaf(a0, b1, c[0][1]);
            c[0][2] = fmaf(a0, b2, c[0][2]); c[0][3] = fmaf(a0, b3, c[0][3]);
            c[1][0] = fmaf(a1, b0, c[1][0]); c[1][1] = fmaf(a1, b1, c[1][1]);
            c[1][2] = fmaf(a1, b2, c[1][2]); c[1][3] = fmaf(a1, b3, c[1][3]);
            c[2][0] = fmaf(a2, b0, c[2][0]); c[2][1] = fmaf(a2, b1, c[2][1]);
            c[2][2] = fmaf(a2, b2, c[2][2]); c[2][3] = fmaf(a2, b3, c[2][3]);
            c[3][0] = fmaf(a3, b0, c[3][0]); c[3][1] = fmaf(a3, b1, c[3][1]);
            c[3][2] = fmaf(a3, b2, c[3][2]); c[3][3] = fmaf(a3, b3, c[3][3]);
        }
    }
    float as0 = 0.f, as1 = 0.f, as2 = 0.f, as3 = 0.f;
    float ad0 = 0.f, ad1 = 0.f, ad2 = 0.f, ad3 = 0.f;
    if (act) {
        as0 = att_src2[4 * ty + 0]; as1 = att_src2[4 * ty + 1];
        as2 = att_src2[4 * ty + 2]; as3 = att_src2[4 * ty + 3];
        ad0 = att_dst2[4 * ty + 0]; ad1 = att_dst2[4 * ty + 1];
        ad2 = att_dst2[4 * ty + 2]; ad3 = att_dst2[4 * ty + 3];
    }
    __syncthreads();                              // reuse sX as partials [row][11]
    float* sPs = sX;
    float* sPd = sX + 64 * 11;
#pragma unroll
    for (int i = 0; i < 4; i++) {
        int row = 4 * tx + i;
        int r = r0 + row;
        if (act) {
            if (r < N) {
                float4 hv = make_float4(c[i][0], c[i][1], c[i][2], c[i][3]);
                *((float4*)(h2 + (size_t)r * 40 + 4 * ty)) = hv;
            }
            sPs[row * 11 + ty] = fmaf(c[i][0], as0, fmaf(c[i][1], as1, fmaf(c[i][2], as2, c[i][3] * as3)));
            sPd[row * 11 + ty] = fmaf(c[i][0], ad0, fmaf(c[i][1], ad1, fmaf(c[i][2], ad2, c[i][3] * ad3)));
        }
    }
    __syncthreads();
    if (t < 64) {
        int r = r0 + t;
        if (r < N) {
            float ps = 0.f, pd = 0.f;
#pragma unroll
            for (int j = 0; j < 10; j++) {
                ps += sPs[t * 11 + j];
                pd += sPd[t * 11 + j];
            }
            a_src2[r] = ps;
            a_dst2[r] = pd;
        }
    }
}

// ---------------- layer 2: per-dst-node softmax + aggregate ----------------
__global__ __launch_bounds__(256) void k_node_agg2(
    const int* __restrict__ deg, const int* __restrict__ ssrc,
    const float* __restrict__ a_src2, const float* __restrict__ a_dst2,
    const float* __restrict__ h2, const float* __restrict__ bias2,
    float* __restrict__ out, int N) {
    int d = (blockIdx.x * 256 + threadIdx.x) >> 6;
    int lane = threadIdx.x & 63;
    if (d >= N) return;
    int start = d << 6;
    int end = start + min(deg[d], SLOT);
    float adst = a_dst2[d];
    bool act = lane < 40;
    float acc0 = 0.0f, acc1 = 0.0f, lsumA = 0.0f;
    for (int base = start; base < end; base += 64) {
        int ecnt = min(64, end - base);
        int s_l = 0; float ex_l = 0.0f;
        if (lane < ecnt) {
            s_l = ssrc[base + lane];
            ex_l = __expf(lrelu(a_src2[s_l] + adst));
        }
        lsumA += ex_l;
        int j = 0;
        for (; j + 8 <= ecnt; j += 8) {
            int s0 = __shfl(s_l, j),     s1 = __shfl(s_l, j + 1), s2 = __shfl(s_l, j + 2), s3 = __shfl(s_l, j + 3);
            int s4 = __shfl(s_l, j + 4), s5 = __shfl(s_l, j + 5), s6 = __shfl(s_l, j + 6), s7 = __shfl(s_l, j + 7);
            float f0 = __shfl(ex_l, j),     f1 = __shfl(ex_l, j + 1), f2 = __shfl(ex_l, j + 2), f3 = __shfl(ex_l, j + 3);
            float f4 = __shfl(ex_l, j + 4), f5 = __shfl(ex_l, j + 5), f6 = __shfl(ex_l, j + 6), f7 = __shfl(ex_l, j + 7);
            float g0 = act ? h2[(size_t)s0 * 40 + lane] : 0.0f;
            float g1 = act ? h2[(size_t)s1 * 40 + lane] : 0.0f;
            float g2 = act ? h2[(size_t)s2 * 40 + lane] : 0.0f;
            float g3 = act ? h2[(size_t)s3 * 40 + lane] : 0.0f;
            float g4 = act ? h2[(size_t)s4 * 40 + lane] : 0.0f;
            float g5 = act ? h2[(size_t)s5 * 40 + lane] : 0.0f;
            float g6 = act ? h2[(size_t)s6 * 40 + lane] : 0.0f;
            float g7 = act ? h2[(size_t)s7 * 40 + lane] : 0.0f;
            acc0 = fmaf(f0, g0, acc0); acc1 = fmaf(f1, g1, acc1);
            acc0 = fmaf(f2, g2, acc0); acc1 = fmaf(f3, g3, acc1);
            acc0 = fmaf(f4, g4, acc0); acc1 = fmaf(f5, g5, acc1);
            acc0 = fmaf(f6, g6, acc0); acc1 = fmaf(f7, g7, acc1);
        }
        for (; j < ecnt; j++) {
            int sj = __shfl(s_l, j);
            float fj = __shfl(ex_l, j);
            float g = act ? h2[(size_t)sj * 40 + lane] : 0.0f;
            acc0 = fmaf(fj, g, acc0);
        }
    }
    float t = lsumA;
#pragma unroll
    for (int off = 32; off; off >>= 1) t += __shfl_xor(t, off);
    if (act) out[(size_t)d * 40 + lane] = (acc0 + acc1) / (t + EPS) + bias2[lane];
}

// ---------------- launch ----------------
extern "C" void kernel_launch(void* const* d_in, const int* in_sizes, int n_in,
                              void* d_out, int out_size, void* d_ws, size_t ws_size,
                              hipStream_t stream) {
    const float* x        = (const float*)d_in[0];
    const int*   ei       = (const int*)d_in[1];
    const float* W1       = (const float*)d_in[2];
    const float* att_src1 = (const float*)d_in[3];
    const float* att_dst1 = (const float*)d_in[4];
    const float* bias1    = (const float*)d_in[5];
    const float* W2       = (const float*)d_in[6];
    const float* att_src2 = (const float*)d_in[7];
    const float* att_dst2 = (const float*)d_in[8];
    const float* bias2    = (const float*)d_in[9];
    float* out = (float*)d_out;

    const int N = in_sizes[0] / 128;   // 50000
    const int E = in_sizes[1] / 2;     // 800000
    const int* src = ei;
    const int* dst = ei + E;

    // workspace layout (slot-CSR: no rowptr/cursor/blocksum; ssrc is N*64 slots)
    float* ws = (float*)d_ws;
    size_t off = 0;
    int*   deg      = (int*)(ws + off); off += (size_t)N;
    int*   ssrc     = (int*)(ws + off); off += (size_t)N * SLOT;
    unsigned short* h1b = (unsigned short*)(ws + off); off += (size_t)N * 32;  // bf16 N*64
    float* a_src1   = ws + off; off += (size_t)N * 8;
    float* a_dst1   = ws + off; off += (size_t)N * 8;
    float* xx       = ws + off; off += (size_t)N * 64;
    float* h2       = ws + off; off += (size_t)N * 40;
    float* a_src2   = ws + off; off += (size_t)N;
    float* a_dst2   = ws + off; off += (size_t)N;

    const int B = 256;
    int G1 = (N + 63) / 64;               // gemm blocks (782)
    int D  = (E / 4 + 255) / 256;         // scatter blocks (4 edges/thread, 782)

    hipMemsetAsync(deg, 0, (size_t)N * sizeof(int), stream);
    // single-pass slot-CSR scatter fused with gemm1 (+ attention dots): scatter blocks
    // first (critical path), GEMM co-schedules behind atomic latency
    k_gemm1_scat<<<D + G1, B, 0, stream>>>(x, W1, att_src1, att_dst1, h1b, a_src1, a_dst1,
                                           N, D, src, dst, deg, ssrc, E);
    k_node_agg1<<<(N + 3) / 4, B, 0, stream>>>(deg, ssrc, a_src1, a_dst1, h1b, bias1, xx, N);
    k_gemm2<<<G1, B, 0, stream>>>(xx, W2, att_src2, att_dst2, h2, a_src2, a_dst2, N);
    k_node_agg2<<<(N + 3) / 4, B, 0, stream>>>(deg, ssrc, a_src2, a_dst2, h2, bias2, out, N);
}

// Round 6
// 228.751 us; speedup vs baseline: 1.1674x; 1.0289x over previous
//
#include <hip/hip_runtime.h>
#include <math.h>

#define EPS 1e-16f
#define SLOT 64
__device__ __forceinline__ float lrelu(float v) { return v > 0.0f ? v : 0.2f * v; }

// bf16 pack/unpack (RNE; inputs finite)
__device__ __forceinline__ unsigned short f2bf(float f) {
    unsigned u = __float_as_uint(f);
    u += 0x7FFF + ((u >> 16) & 1);
    return (unsigned short)(u >> 16);
}
__device__ __forceinline__ float bf2f(unsigned short s) {
    return __uint_as_float(((unsigned)s) << 16);
}

// ---------------- fused: single-pass slot-CSR scatter (blocks [0,D)) + layer-1 GEMM ----------
// Slot-CSR: node d's incoming-edge sources live at ssrc[d*64 .. d*64+deg[d]).
// deg ~ Poisson(16); P(deg>63) ~ 2e-18/node -> 64-slot never overflows (guarded anyway).
// Scatter: 8 edges/thread = 8 independent atomic chains in flight (tests issue-depth vs
// HW atomic-rate limit). Scatter blocks FIRST; GEMM co-schedules behind atomic latency.
// GEMM: x[N,128] @ W1[128,64] -> h1 (bf16), + fused attention dots. BM=64,BN=64,K=128 whole;
// 4x4 micro-tile; pitches 129/65 (==1 mod 32) -> <=2-way conflicts.
#define LDK1 129
#define LDN1 65
__global__ __launch_bounds__(256, 2) void k_gemm1_scat(
    const float* __restrict__ x, const float* __restrict__ W1,
    const float* __restrict__ att_src1, const float* __restrict__ att_dst1,
    unsigned short* __restrict__ h1b, float* __restrict__ a_src1, float* __restrict__ a_dst1,
    int N, int D, const int* __restrict__ src, const int* __restrict__ dst,
    int* __restrict__ deg, int* __restrict__ ssrc, int E) {
    __shared__ float sX[64 * LDK1];    // [m][k]
    __shared__ float sW[128 * LDN1];   // [k][n]
    int t = threadIdx.x;
    if (blockIdx.x < D) {
        int e0 = (blockIdx.x * 256 + t) * 8;
        if (e0 < E) {
            int4 sa = *((const int4*)(src + e0));
            int4 sb = *((const int4*)(src + e0 + 4));
            int4 da = *((const int4*)(dst + e0));
            int4 db = *((const int4*)(dst + e0 + 4));
            int p0 = atomicAdd(&deg[da.x], 1);
            int p1 = atomicAdd(&deg[da.y], 1);
            int p2 = atomicAdd(&deg[da.z], 1);
            int p3 = atomicAdd(&deg[da.w], 1);
            int p4 = atomicAdd(&deg[db.x], 1);
            int p5 = atomicAdd(&deg[db.y], 1);
            int p6 = atomicAdd(&deg[db.z], 1);
            int p7 = atomicAdd(&deg[db.w], 1);
            if (p0 < SLOT) ssrc[(da.x << 6) + p0] = sa.x;
            if (p1 < SLOT) ssrc[(da.y << 6) + p1] = sa.y;
            if (p2 < SLOT) ssrc[(da.z << 6) + p2] = sa.z;
            if (p3 < SLOT) ssrc[(da.w << 6) + p3] = sa.w;
            if (p4 < SLOT) ssrc[(db.x << 6) + p4] = sb.x;
            if (p5 < SLOT) ssrc[(db.y << 6) + p5] = sb.y;
            if (p6 < SLOT) ssrc[(db.z << 6) + p6] = sb.z;
            if (p7 < SLOT) ssrc[(db.w << 6) + p7] = sb.w;
        }
        return;
    }
    int r0 = (blockIdx.x - D) * 64;
    // stage W1 (128x64)
    for (int i = t; i < 2048; i += 256) {        // i = k*16 + n4
        int k = i >> 4, n4 = i & 15;
        float4 v = ((const float4*)W1)[i];
        float* p = sW + k * LDN1 + 4 * n4;
        p[0] = v.x; p[1] = v.y; p[2] = v.z; p[3] = v.w;
    }
    // stage x rows r0..r0+63 (zero-pad tail)
    for (int i = t; i < 2048; i += 256) {        // i = m*32 + k4
        int m = i >> 5, k4 = i & 31;
        int r = r0 + m;
        float4 v = make_float4(0.f, 0.f, 0.f, 0.f);
        if (r < N) v = ((const float4*)(x + (size_t)r * 128))[k4];
        float* p = sX + m * LDK1 + 4 * k4;
        p[0] = v.x; p[1] = v.y; p[2] = v.z; p[3] = v.w;
    }
    __syncthreads();
    int tx = t & 15, ty = t >> 4;                // rows 4*tx.., cols 4*ty..
    const float* pA = sX + 4 * tx * LDK1;
    const float* pB = sW + 4 * ty;
    float c[4][4] = {{0.f}};
#pragma unroll 8
    for (int k = 0; k < 128; k++) {
        float a0 = pA[k], a1 = pA[LDK1 + k], a2 = pA[2 * LDK1 + k], a3 = pA[3 * LDK1 + k];
        const float* pb = pB + k * LDN1;
        float b0 = pb[0], b1 = pb[1], b2 = pb[2], b3 = pb[3];
        c[0][0] = fmaf(a0, b0, c[0][0]); c[0][1] = fmaf(a0, b1, c[0][1]);
        c[0][2] = fmaf(a0, b2, c[0][2]); c[0][3] = fmaf(a0, b3, c[0][3]);
        c[1][0] = fmaf(a1, b0, c[1][0]); c[1][1] = fmaf(a1, b1, c[1][1]);
        c[1][2] = fmaf(a1, b2, c[1][2]); c[1][3] = fmaf(a1, b3, c[1][3]);
        c[2][0] = fmaf(a2, b0, c[2][0]); c[2][1] = fmaf(a2, b1, c[2][1]);
        c[2][2] = fmaf(a2, b2, c[2][2]); c[2][3] = fmaf(a2, b3, c[2][3]);
        c[3][0] = fmaf(a3, b0, c[3][0]); c[3][1] = fmaf(a3, b1, c[3][1]);
        c[3][2] = fmaf(a3, b2, c[3][2]); c[3][3] = fmaf(a3, b3, c[3][3]);
    }
    // epilogue: write h1 as bf16, fused per-head attention dots (fp32 accumulators).
    float as0 = att_src1[4 * ty + 0], as1 = att_src1[4 * ty + 1],
          as2 = att_src1[4 * ty + 2], as3 = att_src1[4 * ty + 3];
    float ad0 = att_dst1[4 * ty + 0], ad1 = att_dst1[4 * ty + 1],
          ad2 = att_dst1[4 * ty + 2], ad3 = att_dst1[4 * ty + 3];
    __syncthreads();                              // done reading sX/sW; reuse sX as partials
    float* sPs = sX;                              // [row][17]
    float* sPd = sX + 64 * 17;
#pragma unroll
    for (int i = 0; i < 4; i++) {
        int row = 4 * tx + i;
        int r = r0 + row;
        if (r < N) {
            ushort4 hv;
            hv.x = f2bf(c[i][0]); hv.y = f2bf(c[i][1]);
            hv.z = f2bf(c[i][2]); hv.w = f2bf(c[i][3]);
            *((ushort4*)(h1b + (size_t)r * 64 + 4 * ty)) = hv;
        }
        sPs[row * 17 + ty] = fmaf(c[i][0], as0, fmaf(c[i][1], as1, fmaf(c[i][2], as2, c[i][3] * as3)));
        sPd[row * 17 + ty] = fmaf(c[i][0], ad0, fmaf(c[i][1], ad1, fmaf(c[i][2], ad2, c[i][3] * ad3)));
    }
    __syncthreads();
    for (int i = t; i < 512; i += 256) {          // i = row*8 + h
        int row = i >> 3, h = i & 7;
        int r = r0 + row;
        if (r < N) {
            a_src1[r * 8 + h] = sPs[row * 17 + 2 * h] + sPs[row * 17 + 2 * h + 1];
            a_dst1[r * 8 + h] = sPd[row * 17 + 2 * h] + sPd[row * 17 + 2 * h + 1];
        }
    }
}

// ---------------- layer 1: per-dst-node softmax + aggregate (one wave per node) ----------------
// MLP-pipelined: coalesced 64-slot row load; phase-A a_src1 gathers batched; phase-B h1b
// gathers 2-deep software-pipelined (chunk c+1's raw ushort loads issue BEFORE chunk c's
// FMAs; bf16->f32 conversion deferred to use). Partial chunks treated as full-8: invalid
// lanes hold s=0 -> row-0 gather (L1-hot) and f=0 kills the contribution exactly.
__global__ __launch_bounds__(256) void k_node_agg1(
    const int* __restrict__ deg, const int* __restrict__ ssrc,
    const float* __restrict__ a_src1, const float* __restrict__ a_dst1,
    const unsigned short* __restrict__ h1b, const float* __restrict__ bias1,
    float* __restrict__ xx, int N) {
    int d = (blockIdx.x * 256 + threadIdx.x) >> 6;
    int lane = threadIdx.x & 63;
    if (d >= N) return;
    int start = d << 6;
    int m = min(deg[d], SLOT);                    // wave-uniform
    int hcol = lane >> 3;   // head owning this output col
    int h8 = lane & 7;      // head this lane covers in edge-parallel phase
    int eoff = lane >> 3;   // edge-in-chunk this lane covers in edge-parallel phase
    float adst8 = a_dst1[d * 8 + h8];
    // coalesced slot-row load: lane i holds src of edge i (0 for i>=m -> safe row-0)
    int s_lane = 0;
    if (lane < m) s_lane = ssrc[start + lane];
    int nch = (m + 7) >> 3;                       // chunks, all treated full-8
    // issue chunk-0 h1b gathers early (fly under phase A's gathers + exp)
    unsigned short rA[8];
#pragma unroll
    for (int j = 0; j < 8; j++) {
        int sj = __shfl(s_lane, j);
        rA[j] = h1b[(size_t)sj * 64 + lane];
    }
    // phase A: per-edge logits, 8 edges x 8 heads in parallel
    float exv[8];
    float lsumA = 0.0f;
#pragma unroll
    for (int c = 0; c < 8; c++) {
        int idx = c * 8 + eoff;
        int s_c = __shfl(s_lane, idx);
        float e = 0.0f;
        if (idx < m) e = __expf(lrelu(a_src1[(size_t)s_c * 8 + h8] + adst8));
        exv[c] = e;
        lsumA += e;
    }
    // phase B: 2-deep pipelined chunks
    float acc0 = 0.0f, acc1 = 0.0f;
#pragma unroll
    for (int c = 0; c < 8; c++) {
        if (c >= nch) break;                      // wave-uniform
        unsigned short rB[8];
        if (c + 1 < nch) {
            int b = (c + 1) * 8;
#pragma unroll
            for (int j = 0; j < 8; j++) {
                int sj = __shfl(s_lane, b + j);
                rB[j] = h1b[(size_t)sj * 64 + lane];
            }
        }
        float exc = exv[c];
        float f0 = __shfl(exc, hcol),      f1 = __shfl(exc, 8 + hcol);
        float f2 = __shfl(exc, 16 + hcol), f3 = __shfl(exc, 24 + hcol);
        float f4 = __shfl(exc, 32 + hcol), f5 = __shfl(exc, 40 + hcol);
        float f6 = __shfl(exc, 48 + hcol), f7 = __shfl(exc, 56 + hcol);
        acc0 = fmaf(f0, bf2f(rA[0]), acc0); acc1 = fmaf(f1, bf2f(rA[1]), acc1);
        acc0 = fmaf(f2, bf2f(rA[2]), acc0); acc1 = fmaf(f3, bf2f(rA[3]), acc1);
        acc0 = fmaf(f4, bf2f(rA[4]), acc0); acc1 = fmaf(f5, bf2f(rA[5]), acc1);
        acc0 = fmaf(f6, bf2f(rA[6]), acc0); acc1 = fmaf(f7, bf2f(rA[7]), acc1);
        if (c + 1 < nch) {
#pragma unroll
            for (int j = 0; j < 8; j++) rA[j] = rB[j];
        }
    }
    // denom: reduce lsumA over edge-offset bits (3..5); then broadcast head hcol's sum
    float t = lsumA;
    t += __shfl_xor(t, 8); t += __shfl_xor(t, 16); t += __shfl_xor(t, 32);
    float lsum = __shfl(t, hcol);
    float o = (acc0 + acc1) / (lsum + EPS) + bias1[lane];
    xx[(size_t)d * 64 + lane] = o > 0.0f ? o : expm1f(o);   // ELU
}

// ---------------- layer 2 GEMM: xx[N,64] @ W2[64,40] -> h2, + fused attention dots ----
#define LDK2 65
#define LDN2 41
__global__ __launch_bounds__(256, 2) void k_gemm2(
    const float* __restrict__ xx, const float* __restrict__ W2,
    const float* __restrict__ att_src2, const float* __restrict__ att_dst2,
    float* __restrict__ h2, float* __restrict__ a_src2, float* __restrict__ a_dst2, int N) {
    __shared__ float sX[64 * LDK2];    // [m][k]
    __shared__ float sW[64 * LDN2];    // [k][n]
    int t = threadIdx.x;
    int r0 = blockIdx.x * 64;
    for (int i = t; i < 640; i += 256) {          // i = k*10 + n4
        int k = i / 10, n4 = i - k * 10;
        float4 v = ((const float4*)W2)[i];
        float* p = sW + k * LDN2 + 4 * n4;
        p[0] = v.x; p[1] = v.y; p[2] = v.z; p[3] = v.w;
    }
    for (int i = t; i < 1024; i += 256) {         // i = m*16 + k4
        int m = i >> 4, k4 = i & 15;
        int r = r0 + m;
        float4 v = make_float4(0.f, 0.f, 0.f, 0.f);
        if (r < N) v = ((const float4*)(xx + (size_t)r * 64))[k4];
        float* p = sX + m * LDK2 + 4 * k4;
        p[0] = v.x; p[1] = v.y; p[2] = v.z; p[3] = v.w;
    }
    __syncthreads();
    int tx = t & 15, ty = t >> 4;
    bool act = ty < 10;
    float c[4][4] = {{0.f}};
    if (act) {
        const float* pA = sX + 4 * tx * LDK2;
        const float* pB = sW + 4 * ty;
#pragma unroll 8
        for (int k = 0; k < 64; k++) {
            float a0 = pA[k], a1 = pA[LDK2 + k], a2 = pA[2 * LDK2 + k], a3 = pA[3 * LDK2 + k];
            const float* pb = pB + k * LDN2;
            float b0 = pb[0], b1 = pb[1], b2 = pb[2], b3 = pb[3];
            c[0][0] = fmaf(a0, b0, c[0][0]); c[0][1] = fmaf(a0, b1, c[0][1]);
            c[0][2] = fmaf(a0, b2, c[0][2]); c[0][3] = fmaf(a0, b3, c[0][3]);
            c[1][0] = fmaf(a1, b0, c[1][0]); c[1][1] = fmaf(a1, b1, c[1][1]);
            c[1][2] = fmaf(a1, b2, c[1][2]); c[1][3] = fmaf(a1, b3, c[1][3]);
            c[2][0] = fmaf(a2, b0, c[2][0]); c[2][1] = fmaf(a2, b1, c[2][1]);
            c[2][2] = fmaf(a2, b2, c[2][2]); c[2][3] = fmaf(a2, b3, c[2][3]);
            c[3][0] = fmaf(a3, b0, c[3][0]); c[3][1] = fmaf(a3, b1, c[3][1]);
            c[3][2] = fmaf(a3, b2, c[3][2]); c[3][3] = fmaf(a3, b3, c[3][3]);
        }
    }
    float as0 = 0.f, as1 = 0.f, as2 = 0.f, as3 = 0.f;
    float ad0 = 0.f, ad1 = 0.f, ad2 = 0.f, ad3 = 0.f;
    if (act) {
        as0 = att_src2[4 * ty + 0]; as1 = att_src2[4 * ty + 1];
        as2 = att_src2[4 * ty + 2]; as3 = att_src2[4 * ty + 3];
        ad0 = att_dst2[4 * ty + 0]; ad1 = att_dst2[4 * ty + 1];
        ad2 = att_dst2[4 * ty + 2]; ad3 = att_dst2[4 * ty + 3];
    }
    __syncthreads();                              // reuse sX as partials [row][11]
    float* sPs = sX;
    float* sPd = sX + 64 * 11;
#pragma unroll
    for (int i = 0; i < 4; i++) {
        int row = 4 * tx + i;
        int r = r0 + row;
        if (act) {
            if (r < N) {
                float4 hv = make_float4(c[i][0], c[i][1], c[i][2], c[i][3]);
                *((float4*)(h2 + (size_t)r * 40 + 4 * ty)) = hv;
            }
            sPs[row * 11 + ty] = fmaf(c[i][0], as0, fmaf(c[i][1], as1, fmaf(c[i][2], as2, c[i][3] * as3)));
            sPd[row * 11 + ty] = fmaf(c[i][0], ad0, fmaf(c[i][1], ad1, fmaf(c[i][2], ad2, c[i][3] * ad3)));
        }
    }
    __syncthreads();
    if (t < 64) {
        int r = r0 + t;
        if (r < N) {
            float ps = 0.f, pd = 0.f;
#pragma unroll
            for (int j = 0; j < 10; j++) {
                ps += sPs[t * 11 + j];
                pd += sPd[t * 11 + j];
            }
            a_src2[r] = ps;
            a_dst2[r] = pd;
        }
    }
}

// ---------------- layer 2: per-dst-node softmax + aggregate (pipelined like agg1) -------------
__global__ __launch_bounds__(256) void k_node_agg2(
    const int* __restrict__ deg, const int* __restrict__ ssrc,
    const float* __restrict__ a_src2, const float* __restrict__ a_dst2,
    const float* __restrict__ h2, const float* __restrict__ bias2,
    float* __restrict__ out, int N) {
    int d = (blockIdx.x * 256 + threadIdx.x) >> 6;
    int lane = threadIdx.x & 63;
    if (d >= N) return;
    int start = d << 6;
    int m = min(deg[d], SLOT);                    // wave-uniform
    float adst = a_dst2[d];
    bool act = lane < 40;
    // coalesced slot-row load; per-lane logit (0 for lane>=m)
    int s_l = 0; float ex_l = 0.0f;
    if (lane < m) {
        s_l = ssrc[start + lane];
        ex_l = __expf(lrelu(a_src2[s_l] + adst));
    }
    int nch = (m + 7) >> 3;
    // chunk-0 gathers issue early
    float gA[8];
#pragma unroll
    for (int j = 0; j < 8; j++) {
        int sj = __shfl(s_l, j);
        gA[j] = act ? h2[(size_t)sj * 40 + lane] : 0.0f;
    }
    float acc0 = 0.0f, acc1 = 0.0f;
#pragma unroll
    for (int c = 0; c < 8; c++) {
        if (c >= nch) break;                      // wave-uniform
        float gB[8];
        if (c + 1 < nch) {
            int b = (c + 1) * 8;
#pragma unroll
            for (int j = 0; j < 8; j++) {
                int sj = __shfl(s_l, b + j);
                gB[j] = act ? h2[(size_t)sj * 40 + lane] : 0.0f;
            }
        }
        int b0 = c * 8;
        float f0 = __shfl(ex_l, b0),     f1 = __shfl(ex_l, b0 + 1);
        float f2 = __shfl(ex_l, b0 + 2), f3 = __shfl(ex_l, b0 + 3);
        float f4 = __shfl(ex_l, b0 + 4), f5 = __shfl(ex_l, b0 + 5);
        float f6 = __shfl(ex_l, b0 + 6), f7 = __shfl(ex_l, b0 + 7);
        acc0 = fmaf(f0, gA[0], acc0); acc1 = fmaf(f1, gA[1], acc1);
        acc0 = fmaf(f2, gA[2], acc0); acc1 = fmaf(f3, gA[3], acc1);
        acc0 = fmaf(f4, gA[4], acc0); acc1 = fmaf(f5, gA[5], acc1);
        acc0 = fmaf(f6, gA[6], acc0); acc1 = fmaf(f7, gA[7], acc1);
        if (c + 1 < nch) {
#pragma unroll
            for (int j = 0; j < 8; j++) gA[j] = gB[j];
        }
    }
    float t = ex_l;
#pragma unroll
    for (int off = 32; off; off >>= 1) t += __shfl_xor(t, off);
    if (act) out[(size_t)d * 40 + lane] = (acc0 + acc1) / (t + EPS) + bias2[lane];
}

// ---------------- launch ----------------
extern "C" void kernel_launch(void* const* d_in, const int* in_sizes, int n_in,
                              void* d_out, int out_size, void* d_ws, size_t ws_size,
                              hipStream_t stream) {
    const float* x        = (const float*)d_in[0];
    const int*   ei       = (const int*)d_in[1];
    const float* W1       = (const float*)d_in[2];
    const float* att_src1 = (const float*)d_in[3];
    const float* att_dst1 = (const float*)d_in[4];
    const float* bias1    = (const float*)d_in[5];
    const float* W2       = (const float*)d_in[6];
    const float* att_src2 = (const float*)d_in[7];
    const float* att_dst2 = (const float*)d_in[8];
    const float* bias2    = (const float*)d_in[9];
    float* out = (float*)d_out;

    const int N = in_sizes[0] / 128;   // 50000
    const int E = in_sizes[1] / 2;     // 800000
    const int* src = ei;
    const int* dst = ei + E;

    // workspace layout (slot-CSR: no rowptr/cursor/blocksum; ssrc is N*64 slots)
    float* ws = (float*)d_ws;
    size_t off = 0;
    int*   deg      = (int*)(ws + off); off += (size_t)N;
    int*   ssrc     = (int*)(ws + off); off += (size_t)N * SLOT;
    unsigned short* h1b = (unsigned short*)(ws + off); off += (size_t)N * 32;  // bf16 N*64
    float* a_src1   = ws + off; off += (size_t)N * 8;
    float* a_dst1   = ws + off; off += (size_t)N * 8;
    float* xx       = ws + off; off += (size_t)N * 64;
    float* h2       = ws + off; off += (size_t)N * 40;
    float* a_src2   = ws + off; off += (size_t)N;
    float* a_dst2   = ws + off; off += (size_t)N;

    const int B = 256;
    int G1 = (N + 63) / 64;               // gemm blocks (782)
    int D  = (E / 8 + 255) / 256;         // scatter blocks (8 edges/thread, 391)

    hipMemsetAsync(deg, 0, (size_t)N * sizeof(int), stream);
    // single-pass slot-CSR scatter fused with gemm1 (+ attention dots): scatter blocks
    // first (critical path), GEMM co-schedules behind atomic latency
    k_gemm1_scat<<<D + G1, B, 0, stream>>>(x, W1, att_src1, att_dst1, h1b, a_src1, a_dst1,
                                           N, D, src, dst, deg, ssrc, E);
    k_node_agg1<<<(N + 3) / 4, B, 0, stream>>>(deg, ssrc, a_src1, a_dst1, h1b, bias1, xx, N);
    k_gemm2<<<G1, B, 0, stream>>>(xx, W2, att_src2, att_dst2, h2, a_src2, a_dst2, N);
    k_node_agg2<<<(N + 3) / 4, B, 0, stream>>>(deg, ssrc, a_src2, a_dst2, h2, bias2, out, N);
}

// Round 7
// 216.779 us; speedup vs baseline: 1.2319x; 1.0552x over previous
//
#include <hip/hip_runtime.h>
#include <math.h>

#define EPS 1e-16f
#define SLOT 64
__device__ __forceinline__ float lrelu(float v) { return v > 0.0f ? v : 0.2f * v; }

// bf16 pack/unpack (RNE; inputs finite)
__device__ __forceinline__ unsigned short f2bf(float f) {
    unsigned u = __float_as_uint(f);
    u += 0x7FFF + ((u >> 16) & 1);
    return (unsigned short)(u >> 16);
}
__device__ __forceinline__ float bf2f(unsigned short s) {
    return __uint_as_float(((unsigned)s) << 16);
}

// ---------------- fused: single-pass slot-CSR scatter (blocks [0,D)) + layer-1 GEMM ----------
// Slot-CSR: node d's incoming-edge sources live at ssrc[d*64 .. d*64+deg[d]).
// deg ~ Poisson(16); P(deg>63) ~ 2e-18/node -> 64-slot never overflows (guarded anyway).
// Scatter: 8 edges/thread = 8 independent atomic chains. Scatter blocks FIRST; GEMM
// co-schedules behind atomic latency.
// GEMM: x[N,128] @ W1[128,64] -> h1 (bf16), + fused attention dots. BM=64,BN=64,K=128 whole;
// 4x4 micro-tile; pitches 129/65 (==1 mod 32) -> <=2-way conflicts.
#define LDK1 129
#define LDN1 65
__global__ __launch_bounds__(256, 2) void k_gemm1_scat(
    const float* __restrict__ x, const float* __restrict__ W1,
    const float* __restrict__ att_src1, const float* __restrict__ att_dst1,
    unsigned short* __restrict__ h1b, float* __restrict__ a_src1, float* __restrict__ a_dst1,
    int N, int D, const int* __restrict__ src, const int* __restrict__ dst,
    int* __restrict__ deg, int* __restrict__ ssrc, int E) {
    __shared__ float sX[64 * LDK1];    // [m][k]
    __shared__ float sW[128 * LDN1];   // [k][n]
    int t = threadIdx.x;
    if (blockIdx.x < D) {
        int e0 = (blockIdx.x * 256 + t) * 8;
        if (e0 < E) {
            int4 sa = *((const int4*)(src + e0));
            int4 sb = *((const int4*)(src + e0 + 4));
            int4 da = *((const int4*)(dst + e0));
            int4 db = *((const int4*)(dst + e0 + 4));
            int p0 = atomicAdd(&deg[da.x], 1);
            int p1 = atomicAdd(&deg[da.y], 1);
            int p2 = atomicAdd(&deg[da.z], 1);
            int p3 = atomicAdd(&deg[da.w], 1);
            int p4 = atomicAdd(&deg[db.x], 1);
            int p5 = atomicAdd(&deg[db.y], 1);
            int p6 = atomicAdd(&deg[db.z], 1);
            int p7 = atomicAdd(&deg[db.w], 1);
            if (p0 < SLOT) ssrc[(da.x << 6) + p0] = sa.x;
            if (p1 < SLOT) ssrc[(da.y << 6) + p1] = sa.y;
            if (p2 < SLOT) ssrc[(da.z << 6) + p2] = sa.z;
            if (p3 < SLOT) ssrc[(da.w << 6) + p3] = sa.w;
            if (p4 < SLOT) ssrc[(db.x << 6) + p4] = sb.x;
            if (p5 < SLOT) ssrc[(db.y << 6) + p5] = sb.y;
            if (p6 < SLOT) ssrc[(db.z << 6) + p6] = sb.z;
            if (p7 < SLOT) ssrc[(db.w << 6) + p7] = sb.w;
        }
        return;
    }
    int r0 = (blockIdx.x - D) * 64;
    // stage W1 (128x64)
    for (int i = t; i < 2048; i += 256) {        // i = k*16 + n4
        int k = i >> 4, n4 = i & 15;
        float4 v = ((const float4*)W1)[i];
        float* p = sW + k * LDN1 + 4 * n4;
        p[0] = v.x; p[1] = v.y; p[2] = v.z; p[3] = v.w;
    }
    // stage x rows r0..r0+63 (zero-pad tail)
    for (int i = t; i < 2048; i += 256) {        // i = m*32 + k4
        int m = i >> 5, k4 = i & 31;
        int r = r0 + m;
        float4 v = make_float4(0.f, 0.f, 0.f, 0.f);
        if (r < N) v = ((const float4*)(x + (size_t)r * 128))[k4];
        float* p = sX + m * LDK1 + 4 * k4;
        p[0] = v.x; p[1] = v.y; p[2] = v.z; p[3] = v.w;
    }
    __syncthreads();
    int tx = t & 15, ty = t >> 4;                // rows 4*tx.., cols 4*ty..
    const float* pA = sX + 4 * tx * LDK1;
    const float* pB = sW + 4 * ty;
    float c[4][4] = {{0.f}};
#pragma unroll 8
    for (int k = 0; k < 128; k++) {
        float a0 = pA[k], a1 = pA[LDK1 + k], a2 = pA[2 * LDK1 + k], a3 = pA[3 * LDK1 + k];
        const float* pb = pB + k * LDN1;
        float b0 = pb[0], b1 = pb[1], b2 = pb[2], b3 = pb[3];
        c[0][0] = fmaf(a0, b0, c[0][0]); c[0][1] = fmaf(a0, b1, c[0][1]);
        c[0][2] = fmaf(a0, b2, c[0][2]); c[0][3] = fmaf(a0, b3, c[0][3]);
        c[1][0] = fmaf(a1, b0, c[1][0]); c[1][1] = fmaf(a1, b1, c[1][1]);
        c[1][2] = fmaf(a1, b2, c[1][2]); c[1][3] = fmaf(a1, b3, c[1][3]);
        c[2][0] = fmaf(a2, b0, c[2][0]); c[2][1] = fmaf(a2, b1, c[2][1]);
        c[2][2] = fmaf(a2, b2, c[2][2]); c[2][3] = fmaf(a2, b3, c[2][3]);
        c[3][0] = fmaf(a3, b0, c[3][0]); c[3][1] = fmaf(a3, b1, c[3][1]);
        c[3][2] = fmaf(a3, b2, c[3][2]); c[3][3] = fmaf(a3, b3, c[3][3]);
    }
    // epilogue: write h1 as bf16, fused per-head attention dots (fp32 accumulators).
    float as0 = att_src1[4 * ty + 0], as1 = att_src1[4 * ty + 1],
          as2 = att_src1[4 * ty + 2], as3 = att_src1[4 * ty + 3];
    float ad0 = att_dst1[4 * ty + 0], ad1 = att_dst1[4 * ty + 1],
          ad2 = att_dst1[4 * ty + 2], ad3 = att_dst1[4 * ty + 3];
    __syncthreads();                              // done reading sX/sW; reuse sX as partials
    float* sPs = sX;                              // [row][17]
    float* sPd = sX + 64 * 17;
#pragma unroll
    for (int i = 0; i < 4; i++) {
        int row = 4 * tx + i;
        int r = r0 + row;
        if (r < N) {
            ushort4 hv;
            hv.x = f2bf(c[i][0]); hv.y = f2bf(c[i][1]);
            hv.z = f2bf(c[i][2]); hv.w = f2bf(c[i][3]);
            *((ushort4*)(h1b + (size_t)r * 64 + 4 * ty)) = hv;
        }
        sPs[row * 17 + ty] = fmaf(c[i][0], as0, fmaf(c[i][1], as1, fmaf(c[i][2], as2, c[i][3] * as3)));
        sPd[row * 17 + ty] = fmaf(c[i][0], ad0, fmaf(c[i][1], ad1, fmaf(c[i][2], ad2, c[i][3] * ad3)));
    }
    __syncthreads();
    for (int i = t; i < 512; i += 256) {          // i = row*8 + h
        int row = i >> 3, h = i & 7;
        int r = r0 + row;
        if (r < N) {
            a_src1[r * 8 + h] = sPs[row * 17 + 2 * h] + sPs[row * 17 + 2 * h + 1];
            a_dst1[r * 8 + h] = sPd[row * 17 + 2 * h] + sPd[row * 17 + 2 * h + 1];
        }
    }
}

// ---------------- layer 1: per-dst-node softmax + aggregate (one wave per node) ----------------
// Dual-row gathers: each lane loads a uint (2 bf16 cols); lanes 0-31 cover row A, lanes
// 32-63 cover row B -> ONE instruction gathers TWO h1b rows (was one). Gather + shuffle
// instruction count halves. Lane l accumulates col pair (2q,2q+1), q=l&31, over its
// edge-parity half (sub=l>>5); halves merged with one shfl_xor(32) at the end.
// Partial chunks: invalid edges have exv=0 and row 0 (s=0) -> exact zero contribution.
__global__ __launch_bounds__(256) void k_node_agg1(
    const int* __restrict__ deg, const int* __restrict__ ssrc,
    const float* __restrict__ a_src1, const float* __restrict__ a_dst1,
    const unsigned short* __restrict__ h1b, const float* __restrict__ bias1,
    float* __restrict__ xx, int N) {
    int d = (blockIdx.x * 256 + threadIdx.x) >> 6;
    int lane = threadIdx.x & 63;
    if (d >= N) return;
    int start = d << 6;
    int m = min(deg[d], SLOT);                    // wave-uniform
    int h8 = lane & 7;      // head this lane covers in phase A
    int eoff = lane >> 3;   // edge-in-chunk this lane covers in phase A
    int q = lane & 31;      // col-pair index: cols 2q, 2q+1
    int hsel = q >> 2;      // head owning the col pair
    int sub = lane >> 5;    // 0: even edges-in-pair, 1: odd
    float adst8 = a_dst1[d * 8 + h8];
    // coalesced slot-row load: lane i holds src of edge i (0 for i>=m -> safe row-0)
    int s_lane = 0;
    if (lane < m) s_lane = ssrc[start + lane];
    int nch = (m + 7) >> 3;                       // 8-edge chunks
    // prime chunk-0 gathers (4 dual-row uint loads), fly under phase A
    unsigned rA[4];
#pragma unroll
    for (int k = 0; k < 4; k++) {
        int sR = __shfl(s_lane, 2 * k + sub);
        rA[k] = *((const unsigned*)(h1b + (size_t)sR * 64 + (q << 1)));
    }
    // phase A: per-edge logits, 8 edges x 8 heads in parallel
    float exv[8];
    float lsumA = 0.0f;
#pragma unroll
    for (int c = 0; c < 8; c++) {
        int idx = c * 8 + eoff;
        int s_c = __shfl(s_lane, idx);
        float e = 0.0f;
        if (idx < m) e = __expf(lrelu(a_src1[(size_t)s_c * 8 + h8] + adst8));
        exv[c] = e;
        lsumA += e;
    }
    // phase B: 2-deep pipelined chunks, 4 dual-row gathers per chunk
    float accLo = 0.0f, accHi = 0.0f;
#pragma unroll
    for (int c = 0; c < 8; c++) {
        if (c >= nch) break;                      // wave-uniform
        unsigned rB[4];
        if (c + 1 < nch) {
#pragma unroll
            for (int k = 0; k < 4; k++) {
                int sR = __shfl(s_lane, (c + 1) * 8 + 2 * k + sub);
                rB[k] = *((const unsigned*)(h1b + (size_t)sR * 64 + (q << 1)));
            }
        }
#pragma unroll
        for (int k = 0; k < 4; k++) {
            float f = __shfl(exv[c], ((2 * k + sub) << 3) | hsel);
            accLo = fmaf(f, bf2f((unsigned short)(rA[k] & 0xffff)), accLo);
            accHi = fmaf(f, bf2f((unsigned short)(rA[k] >> 16)), accHi);
        }
        if (c + 1 < nch) {
#pragma unroll
            for (int k = 0; k < 4; k++) rA[k] = rB[k];
        }
    }
    // merge even/odd edge halves (lane l <-> l+32 hold same col pair)
    accLo += __shfl_xor(accLo, 32);
    accHi += __shfl_xor(accHi, 32);
    // denom: reduce lsumA over edge-offset bits (3..5) -> per-head sums; broadcast
    float t = lsumA;
    t += __shfl_xor(t, 8); t += __shfl_xor(t, 16); t += __shfl_xor(t, 32);
    float lsum = __shfl(t, hsel);
    if (lane < 32) {
        float2 bz = ((const float2*)bias1)[q];
        float oLo = accLo / (lsum + EPS) + bz.x;
        float oHi = accHi / (lsum + EPS) + bz.y;
        oLo = oLo > 0.0f ? oLo : expm1f(oLo);     // ELU
        oHi = oHi > 0.0f ? oHi : expm1f(oHi);
        *((float2*)(xx + (size_t)d * 64 + 2 * q)) = make_float2(oLo, oHi);
    }
}

// ---------------- layer 2 GEMM: xx[N,64] @ W2[64,40] -> h2, + fused attention dots ----
#define LDK2 65
#define LDN2 41
__global__ __launch_bounds__(256, 2) void k_gemm2(
    const float* __restrict__ xx, const float* __restrict__ W2,
    const float* __restrict__ att_src2, const float* __restrict__ att_dst2,
    float* __restrict__ h2, float* __restrict__ a_src2, float* __restrict__ a_dst2, int N) {
    __shared__ float sX[64 * LDK2];    // [m][k]
    __shared__ float sW[64 * LDN2];    // [k][n]
    int t = threadIdx.x;
    int r0 = blockIdx.x * 64;
    for (int i = t; i < 640; i += 256) {          // i = k*10 + n4
        int k = i / 10, n4 = i - k * 10;
        float4 v = ((const float4*)W2)[i];
        float* p = sW + k * LDN2 + 4 * n4;
        p[0] = v.x; p[1] = v.y; p[2] = v.z; p[3] = v.w;
    }
    for (int i = t; i < 1024; i += 256) {         // i = m*16 + k4
        int m = i >> 4, k4 = i & 15;
        int r = r0 + m;
        float4 v = make_float4(0.f, 0.f, 0.f, 0.f);
        if (r < N) v = ((const float4*)(xx + (size_t)r * 64))[k4];
        float* p = sX + m * LDK2 + 4 * k4;
        p[0] = v.x; p[1] = v.y; p[2] = v.z; p[3] = v.w;
    }
    __syncthreads();
    int tx = t & 15, ty = t >> 4;
    bool act = ty < 10;
    float c[4][4] = {{0.f}};
    if (act) {
        const float* pA = sX + 4 * tx * LDK2;
        const float* pB = sW + 4 * ty;
#pragma unroll 8
        for (int k = 0; k < 64; k++) {
            float a0 = pA[k], a1 = pA[LDK2 + k], a2 = pA[2 * LDK2 + k], a3 = pA[3 * LDK2 + k];
            const float* pb = pB + k * LDN2;
            float b0 = pb[0], b1 = pb[1], b2 = pb[2], b3 = pb[3];
            c[0][0] = fmaf(a0, b0, c[0][0]); c[0][1] = fmaf(a0, b1, c[0][1]);
            c[0][2] = fmaf(a0, b2, c[0][2]); c[0][3] = fmaf(a0, b3, c[0][3]);
            c[1][0] = fmaf(a1, b0, c[1][0]); c[1][1] = fmaf(a1, b1, c[1][1]);
            c[1][2] = fmaf(a1, b2, c[1][2]); c[1][3] = fmaf(a1, b3, c[1][3]);
            c[2][0] = fmaf(a2, b0, c[2][0]); c[2][1] = fmaf(a2, b1, c[2][1]);
            c[2][2] = fmaf(a2, b2, c[2][2]); c[2][3] = fmaf(a2, b3, c[2][3]);
            c[3][0] = fmaf(a3, b0, c[3][0]); c[3][1] = fmaf(a3, b1, c[3][1]);
            c[3][2] = fmaf(a3, b2, c[3][2]); c[3][3] = fmaf(a3, b3, c[3][3]);
        }
    }
    float as0 = 0.f, as1 = 0.f, as2 = 0.f, as3 = 0.f;
    float ad0 = 0.f, ad1 = 0.f, ad2 = 0.f, ad3 = 0.f;
    if (act) {
        as0 = att_src2[4 * ty + 0]; as1 = att_src2[4 * ty + 1];
        as2 = att_src2[4 * ty + 2]; as3 = att_src2[4 * ty + 3];
        ad0 = att_dst2[4 * ty + 0]; ad1 = att_dst2[4 * ty + 1];
        ad2 = att_dst2[4 * ty + 2]; ad3 = att_dst2[4 * ty + 3];
    }
    __syncthreads();                              // reuse sX as partials [row][11]
    float* sPs = sX;
    float* sPd = sX + 64 * 11;
#pragma unroll
    for (int i = 0; i < 4; i++) {
        int row = 4 * tx + i;
        int r = r0 + row;
        if (act) {
            if (r < N) {
                float4 hv = make_float4(c[i][0], c[i][1], c[i][2], c[i][3]);
                *((float4*)(h2 + (size_t)r * 40 + 4 * ty)) = hv;
            }
            sPs[row * 11 + ty] = fmaf(c[i][0], as0, fmaf(c[i][1], as1, fmaf(c[i][2], as2, c[i][3] * as3)));
            sPd[row * 11 + ty] = fmaf(c[i][0], ad0, fmaf(c[i][1], ad1, fmaf(c[i][2], ad2, c[i][3] * ad3)));
        }
    }
    __syncthreads();
    if (t < 64) {
        int r = r0 + t;
        if (r < N) {
            float ps = 0.f, pd = 0.f;
#pragma unroll
            for (int j = 0; j < 10; j++) {
                ps += sPs[t * 11 + j];
                pd += sPd[t * 11 + j];
            }
            a_src2[r] = ps;
            a_dst2[r] = pd;
        }
    }
}

// ---------------- layer 2: per-dst-node softmax + aggregate ----------------
// Triple-row gathers: each lane loads a float2 (2 cols of a 40-col h2 row); 20 lanes/row ->
// one instruction covers THREE rows (lanes 60-63 idle). Gather instruction count -> m/3.
// Lane accumulates col pair (2*q20, 2*q20+1) over edges j==grp (mod 3); groups merged with
// two indexed shuffles. Invalid j -> f=0 with safe row (clamped shuffle index).
__global__ __launch_bounds__(256) void k_node_agg2(
    const int* __restrict__ deg, const int* __restrict__ ssrc,
    const float* __restrict__ a_src2, const float* __restrict__ a_dst2,
    const float* __restrict__ h2, const float* __restrict__ bias2,
    float* __restrict__ out, int N) {
    int d = (blockIdx.x * 256 + threadIdx.x) >> 6;
    int lane = threadIdx.x & 63;
    if (d >= N) return;
    int start = d << 6;
    int m = min(deg[d], SLOT);                    // wave-uniform
    float adst = a_dst2[d];
    // coalesced slot-row load; per-lane logit (0 for lane>=m)
    int s_l = 0; float ex_l = 0.0f;
    if (lane < m) {
        s_l = ssrc[start + lane];
        ex_l = __expf(lrelu(a_src2[s_l] + adst));
    }
    int grp = lane / 20;                          // 0,1,2 gather groups; 3 = idle lanes
    int q20 = lane - grp * 20;                    // col-pair index within row
    bool gact = grp < 3;
    int nin = (m + 2) / 3;                        // gather instructions
    int nblk = (nin + 3) >> 2;                    // blocks of 4 instructions (<=6)
    float aLo = 0.0f, aHi = 0.0f;
    auto loadb = [&](int b, float2* g, float* f) {
#pragma unroll
        for (int k2 = 0; k2 < 4; k2++) {
            int j = 3 * (4 * b + k2) + grp;       // edge index
            int jm = j & 63;                      // clamp for shuffle validity
            int sR = __shfl(s_l, jm);
            float fv = __shfl(ex_l, jm);
            f[k2] = (gact && j < m) ? fv : 0.0f;
            g[k2] = *((const float2*)(h2 + (size_t)sR * 40 + 2 * q20));
        }
    };
    float2 gA[4]; float fA[4];
    if (nblk > 0) loadb(0, gA, fA);
#pragma unroll
    for (int b = 0; b < 6; b++) {
        if (b >= nblk) break;                     // wave-uniform
        float2 gB[4]; float fB[4];
        if (b + 1 < nblk) loadb(b + 1, gB, fB);
#pragma unroll
        for (int k2 = 0; k2 < 4; k2++) {
            aLo = fmaf(fA[k2], gA[k2].x, aLo);
            aHi = fmaf(fA[k2], gA[k2].y, aHi);
        }
        if (b + 1 < nblk) {
#pragma unroll
            for (int k2 = 0; k2 < 4; k2++) { gA[k2] = gB[k2]; fA[k2] = fB[k2]; }
        }
    }
    // merge the 3 edge groups (lanes l, l+20, l+40 hold the same col pair)
    int i1 = (lane + 20) & 63, i2 = (lane + 40) & 63;
    float ml1 = __shfl(aLo, i1), ml2 = __shfl(aLo, i2);
    float mh1 = __shfl(aHi, i1), mh2 = __shfl(aHi, i2);
    aLo += ml1 + ml2;
    aHi += mh1 + mh2;
    // denominator: full-wave reduce of per-lane logits
    float t = ex_l;
#pragma unroll
    for (int off = 32; off; off >>= 1) t += __shfl_xor(t, off);
    if (lane < 20) {
        float2 bz = ((const float2*)bias2)[lane];
        float oLo = aLo / (t + EPS) + bz.x;
        float oHi = aHi / (t + EPS) + bz.y;
        *((float2*)(out + (size_t)d * 40 + 2 * lane)) = make_float2(oLo, oHi);
    }
}

// ---------------- launch ----------------
extern "C" void kernel_launch(void* const* d_in, const int* in_sizes, int n_in,
                              void* d_out, int out_size, void* d_ws, size_t ws_size,
                              hipStream_t stream) {
    const float* x        = (const float*)d_in[0];
    const int*   ei       = (const int*)d_in[1];
    const float* W1       = (const float*)d_in[2];
    const float* att_src1 = (const float*)d_in[3];
    const float* att_dst1 = (const float*)d_in[4];
    const float* bias1    = (const float*)d_in[5];
    const float* W2       = (const float*)d_in[6];
    const float* att_src2 = (const float*)d_in[7];
    const float* att_dst2 = (const float*)d_in[8];
    const float* bias2    = (const float*)d_in[9];
    float* out = (float*)d_out;

    const int N = in_sizes[0] / 128;   // 50000
    const int E = in_sizes[1] / 2;     // 800000
    const int* src = ei;
    const int* dst = ei + E;

    // workspace layout (slot-CSR: no rowptr/cursor/blocksum; ssrc is N*64 slots)
    float* ws = (float*)d_ws;
    size_t off = 0;
    int*   deg      = (int*)(ws + off); off += (size_t)N;
    int*   ssrc     = (int*)(ws + off); off += (size_t)N * SLOT;
    unsigned short* h1b = (unsigned short*)(ws + off); off += (size_t)N * 32;  // bf16 N*64
    float* a_src1   = ws + off; off += (size_t)N * 8;
    float* a_dst1   = ws + off; off += (size_t)N * 8;
    float* xx       = ws + off; off += (size_t)N * 64;
    float* h2       = ws + off; off += (size_t)N * 40;
    float* a_src2   = ws + off; off += (size_t)N;
    float* a_dst2   = ws + off; off += (size_t)N;

    const int B = 256;
    int G1 = (N + 63) / 64;               // gemm blocks (782)
    int D  = (E / 8 + 255) / 256;         // scatter blocks (8 edges/thread, 391)

    hipMemsetAsync(deg, 0, (size_t)N * sizeof(int), stream);
    // single-pass slot-CSR scatter fused with gemm1 (+ attention dots): scatter blocks
    // first (critical path), GEMM co-schedules behind atomic latency
    k_gemm1_scat<<<D + G1, B, 0, stream>>>(x, W1, att_src1, att_dst1, h1b, a_src1, a_dst1,
                                           N, D, src, dst, deg, ssrc, E);
    k_node_agg1<<<(N + 3) / 4, B, 0, stream>>>(deg, ssrc, a_src1, a_dst1, h1b, bias1, xx, N);
    k_gemm2<<<G1, B, 0, stream>>>(xx, W2, att_src2, att_dst2, h2, a_src2, a_dst2, N);
    k_node_agg2<<<(N + 3) / 4, B, 0, stream>>>(deg, ssrc, a_src2, a_dst2, h2, bias2, out, N);
}